// Round 7
// baseline (220.396 us; speedup 1.0000x reference)
//
#include <hip/hip_runtime.h>
#include <hip/hip_bf16.h>
#include <cmath>

// Problem constants
#define BATCH   16
#define SEQ     2048
#define IN_DIM  57
#define D_MODEL 64
#define HEADDIM 32
#define D_STATE 32
#define OUT_DIM 6
#define D_INNER 128
#define NHEADS  4
#define D_CONV  4
#define D_XBC   192          // D_INNER + 2*D_STATE
#define D_IN_PROJ 324        // 2*D_INNER + 2*D_STATE + NHEADS
#define BL      (BATCH*SEQ)  // 32768

// Chunked scan config
#define NCHUNK  32
#define CLEN    (SEQ / NCHUNK)   // 64

// inproj tiling
#define RTILE   24
#define XPAD    60

// conv_dt chunking
#define CCH     16

// Workspace layout (floats)
#define OFF_WF   ((size_t)0)
#define OFF_BF   ((size_t)18496)
#define OFF_ZX   ((size_t)18848)
#define OFF_XBC  (OFF_ZX  + (size_t)BL*D_IN_PROJ)
#define OFF_DD   (OFF_XBC + (size_t)BL*D_XBC)      // BL*8 interleaved {dt,dec}x4
#define OFF_Y    (OFF_DD  + (size_t)BL*8)
#define OFF_G    (OFF_Y   + (size_t)BL*D_INNER)
#define OFF_WOC  (OFF_G   + (size_t)2048)
#define OFF_SB   (OFF_WOC + (size_t)896)           // 64*NCHUNK*1024 chunk states
#define OFF_P    (OFF_SB  + (size_t)64*NCHUNK*1024)
// total ~ 23.5M floats ~ 94 MB (same as prior round)

// ---------------------------------------------------------------------------
// Kernel 1: Wf = W_lin@W_in ; bf = b_lin@W_in ; W_oc = W_out@W_cls
__global__ void fuse_w_kernel(const float* __restrict__ W_lin,
                              const float* __restrict__ b_lin,
                              const float* __restrict__ W_in,
                              const float* __restrict__ W_out,
                              const float* __restrict__ W_cls,
                              float* __restrict__ Wf, float* __restrict__ bf,
                              float* __restrict__ Woc) {
    int idx = blockIdx.x * 256 + threadIdx.x;
    if (idx < 58 * D_IN_PROJ) {
        int r = idx / D_IN_PROJ;
        int j = idx - r * D_IN_PROJ;
        const float* v = (r < IN_DIM) ? (W_lin + r * D_MODEL) : b_lin;
        float acc = 0.f;
#pragma unroll 8
        for (int m = 0; m < D_MODEL; ++m) acc += v[m] * W_in[m * D_IN_PROJ + j];
        if (r < IN_DIM) Wf[r * D_IN_PROJ + j] = acc;
        else            bf[j] = acc;
    } else if (idx < 58 * D_IN_PROJ + D_INNER * OUT_DIM) {
        int idx2 = idx - 58 * D_IN_PROJ;
        int i = idx2 / OUT_DIM;
        int o = idx2 - i * OUT_DIM;
        float acc = 0.f;
#pragma unroll 8
        for (int j = 0; j < D_MODEL; ++j)
            acc += W_out[i * D_MODEL + j] * W_cls[j * OUT_DIM + o];
        Woc[i * OUT_DIM + o] = acc;
    }
}

// ---------------------------------------------------------------------------
// Kernel 2: LDS-staged in-projection. Block: 24 rows x 324 cols.
__global__ __launch_bounds__(256) void inproj_kernel(
        const float* __restrict__ x,
        const float* __restrict__ Wf,
        const float* __restrict__ bf,
        float* __restrict__ zx) {
    __shared__ float xs[RTILE][XPAD];
    int r0 = blockIdx.x * RTILE;
    for (int i = threadIdx.x; i < RTILE * IN_DIM; i += 256) {
        size_t g = (size_t)r0 * IN_DIM + i;
        float v = (g < (size_t)BL * IN_DIM) ? x[g] : 0.f;
        xs[i / IN_DIM][i % IN_DIM] = v;
    }
    __syncthreads();
    if (threadIdx.x >= 243) return;
    int rset = threadIdx.x / 81;
    int cg   = threadIdx.x - rset * 81;
    int j0   = cg * 4;
    float4 bias = *(const float4*)(bf + j0);
    float4 acc[8];
#pragma unroll
    for (int r = 0; r < 8; ++r) acc[r] = bias;
    const float* w = Wf + j0;
    const float* xrow = &xs[rset * 8][0];
#pragma unroll 2
    for (int kc = 0; kc < 14; ++kc) {
        int k = kc * 4;
        float4 wv0 = *(const float4*)(w + (size_t)(k + 0) * D_IN_PROJ);
        float4 wv1 = *(const float4*)(w + (size_t)(k + 1) * D_IN_PROJ);
        float4 wv2 = *(const float4*)(w + (size_t)(k + 2) * D_IN_PROJ);
        float4 wv3 = *(const float4*)(w + (size_t)(k + 3) * D_IN_PROJ);
#pragma unroll
        for (int r = 0; r < 8; ++r) {
            float4 xv = *(const float4*)(xrow + r * XPAD + k);
            acc[r].x += xv.x * wv0.x + xv.y * wv1.x + xv.z * wv2.x + xv.w * wv3.x;
            acc[r].y += xv.x * wv0.y + xv.y * wv1.y + xv.z * wv2.y + xv.w * wv3.y;
            acc[r].z += xv.x * wv0.z + xv.y * wv1.z + xv.z * wv2.z + xv.w * wv3.z;
            acc[r].w += xv.x * wv0.w + xv.y * wv1.w + xv.z * wv2.w + xv.w * wv3.w;
        }
    }
    {
        float4 wv = *(const float4*)(w + (size_t)56 * D_IN_PROJ);
#pragma unroll
        for (int r = 0; r < 8; ++r) {
            float xv = xrow[r * XPAD + 56];
            acc[r].x += xv * wv.x; acc[r].y += xv * wv.y;
            acc[r].z += xv * wv.z; acc[r].w += xv * wv.w;
        }
    }
#pragma unroll
    for (int r = 0; r < 8; ++r) {
        int row = r0 + rset * 8 + r;
        if (row < BL)
            *(float4*)(zx + (size_t)row * D_IN_PROJ + j0) = acc[r];
    }
}

// ---------------------------------------------------------------------------
// Kernel 3: depthwise causal conv(4) + bias + SiLU; dt softplus; decay exp(dt*A).
// Writes interleaved ddc[bl][8] = {dt0,dec0, dt1,dec1, dt2,dec2, dt3,dec3}.
__global__ __launch_bounds__(256) void conv_dt_kernel(
        const float* __restrict__ zx,
        const float* __restrict__ conv_w,
        const float* __restrict__ conv_b,
        const float* __restrict__ dt_bias,
        const float* __restrict__ A_log,
        float* __restrict__ xBC,
        float* __restrict__ ddc) {
    int b = blockIdx.x >> 7;          // SEQ/CCH = 128 chunks
    int c = blockIdx.x & 127;
    int l0 = c * CCH;
    int tid = threadIdx.x;
    size_t bl0 = (size_t)b * SEQ + l0;
    if (tid < D_XBC) {
        float w0 = conv_w[tid*4+0], w1 = conv_w[tid*4+1];
        float w2 = conv_w[tid*4+2], w3 = conv_w[tid*4+3];
        float cb = conv_b[tid];
        const float* src = zx + bl0 * D_IN_PROJ + D_INNER + tid;
        float vm1 = 0.f, vm2 = 0.f, vm3 = 0.f;
        if (c > 0) {
            vm1 = src[-(int)D_IN_PROJ];
            vm2 = src[-2*(int)D_IN_PROJ];
            vm3 = src[-3*(int)D_IN_PROJ];
        }
        float* dst = xBC + bl0 * D_XBC + tid;
#pragma unroll
        for (int i = 0; i < CCH; ++i) {
            float v0 = src[(size_t)i * D_IN_PROJ];
            float a = cb + v0 * w3 + vm1 * w2 + vm2 * w1 + vm3 * w0;
            dst[(size_t)i * D_XBC] = a / (1.f + expf(-a));   // SiLU
            vm3 = vm2; vm2 = vm1; vm1 = v0;
        }
    } else if (tid < D_XBC + NHEADS) {
        int h = tid - D_XBC;
        float bias = dt_bias[h];
        float A = -expf(A_log[h]);
        const float* src = zx + bl0 * D_IN_PROJ + 320 + h;
        float* dd = ddc + bl0 * 8 + h * 2;
#pragma unroll
        for (int i = 0; i < CCH; ++i) {
            float v = src[(size_t)i * D_IN_PROJ] + bias;
            float dtv = (v > 20.f) ? v : log1pf(expf(v));
            dd[(size_t)i * 8]     = dtv;
            dd[(size_t)i * 8 + 1] = expf(dtv * A);
        }
    }
}

// ---------------------------------------------------------------------------
// Chunked scan, phase 1. Block = (b, chunk); wave = head; lane -> (p = lane>>1,
// n-half = (lane&1)*16). 16 state floats per lane. s0..s3 cover n0..n0+15.
__global__ __launch_bounds__(256) void scan_phase1_kernel(
        const float* __restrict__ xBC, const float* __restrict__ ddc,
        float* __restrict__ sbuf, float* __restrict__ Pbuf) {
    int b = blockIdx.x >> 5;          // NCHUNK=32
    int c = blockIdx.x & 31;
    int h = threadIdx.x >> 6;
    int lane = threadIdx.x & 63;
    int p = lane >> 1;
    int n0 = (lane & 1) * 16;
    float4 s0 = make_float4(0.f,0.f,0.f,0.f), s1 = s0, s2 = s0, s3 = s0;
    float pacc = 1.f;
    size_t rbase = (size_t)b * SEQ + (size_t)c * CLEN;
    const float* xrow = xBC + rbase * D_XBC;
    const float* dd = ddc + rbase * 8 + h * 2;
#pragma unroll 4
    for (int i = 0; i < CLEN; ++i) {
        const float* row = xrow + (size_t)i * D_XBC;
        float2 dv = *(const float2*)(dd + (size_t)i * 8);
        float xv = row[h * HEADDIM + p];
        const float* Bp = row + D_INNER + n0;
        float4 B0 = *(const float4*)(Bp + 0);
        float4 B1 = *(const float4*)(Bp + 4);
        float4 B2 = *(const float4*)(Bp + 8);
        float4 B3 = *(const float4*)(Bp + 12);
        float coef = dv.x * xv;
        float dec  = dv.y;
        s0.x = s0.x*dec + coef*B0.x; s0.y = s0.y*dec + coef*B0.y;
        s0.z = s0.z*dec + coef*B0.z; s0.w = s0.w*dec + coef*B0.w;
        s1.x = s1.x*dec + coef*B1.x; s1.y = s1.y*dec + coef*B1.y;
        s1.z = s1.z*dec + coef*B1.z; s1.w = s1.w*dec + coef*B1.w;
        s2.x = s2.x*dec + coef*B2.x; s2.y = s2.y*dec + coef*B2.y;
        s2.z = s2.z*dec + coef*B2.z; s2.w = s2.w*dec + coef*B2.w;
        s3.x = s3.x*dec + coef*B3.x; s3.y = s3.y*dec + coef*B3.y;
        s3.z = s3.z*dec + coef*B3.z; s3.w = s3.w*dec + coef*B3.w;
        pacc *= dec;
    }
    int bh = b * NHEADS + h;
    float4* sp = (float4*)sbuf + ((size_t)bh * NCHUNK + c) * 256;
    sp[0*64 + lane] = s0;
    sp[1*64 + lane] = s1;
    sp[2*64 + lane] = s2;
    sp[3*64 + lane] = s3;
    if (lane == 0) Pbuf[bh * NCHUNK + c] = pacc;
}

// ---------------------------------------------------------------------------
// Phase 2: combine chunk states. Grid 256 blocks; thread = one float slot,
// coalesced 1KB per iteration. sbuf[c] <- initial state for chunk c.
__global__ __launch_bounds__(256) void scan_phase2_kernel(
        float* __restrict__ sbuf, const float* __restrict__ Pbuf) {
    int bh = blockIdx.x >> 2;
    int q  = blockIdx.x & 3;
    int idx = q * 256 + threadIdx.x;     // 0..1023
    float run = 0.f;
    for (int c = 0; c < NCHUNK; ++c) {
        size_t a = ((size_t)bh * NCHUNK + c) * 1024 + idx;
        float tmp = sbuf[a];
        float Pv = Pbuf[bh * NCHUNK + c];
        sbuf[a] = run;
        run = run * Pv + tmp;
    }
}

// ---------------------------------------------------------------------------
// Phase 3: seeded re-run producing y.
__global__ __launch_bounds__(256) void scan_phase3_kernel(
        const float* __restrict__ xBC, const float* __restrict__ ddc,
        const float* __restrict__ Dp, const float* __restrict__ sbuf,
        float* __restrict__ yraw) {
    int b = blockIdx.x >> 5;
    int c = blockIdx.x & 31;
    int h = threadIdx.x >> 6;
    int lane = threadIdx.x & 63;
    int p = lane >> 1;
    int n0 = (lane & 1) * 16;
    int bh = b * NHEADS + h;
    const float4* sp = (const float4*)sbuf + ((size_t)bh * NCHUNK + c) * 256;
    float4 s0 = sp[0*64 + lane];
    float4 s1 = sp[1*64 + lane];
    float4 s2 = sp[2*64 + lane];
    float4 s3 = sp[3*64 + lane];
    float Dh = Dp[h];
    size_t rbase = (size_t)b * SEQ + (size_t)c * CLEN;
    const float* xrow = xBC + rbase * D_XBC;
    const float* dd = ddc + rbase * 8 + h * 2;
    float* yp = yraw + rbase * D_INNER + h * HEADDIM + p;
#pragma unroll 4
    for (int i = 0; i < CLEN; ++i) {
        const float* row = xrow + (size_t)i * D_XBC;
        float2 dv = *(const float2*)(dd + (size_t)i * 8);
        float xv = row[h * HEADDIM + p];
        const float* Bp = row + D_INNER + n0;
        const float* Cp = row + D_INNER + D_STATE + n0;
        float4 B0 = *(const float4*)(Bp + 0);
        float4 B1 = *(const float4*)(Bp + 4);
        float4 B2 = *(const float4*)(Bp + 8);
        float4 B3 = *(const float4*)(Bp + 12);
        float4 C0 = *(const float4*)(Cp + 0);
        float4 C1 = *(const float4*)(Cp + 4);
        float4 C2 = *(const float4*)(Cp + 8);
        float4 C3 = *(const float4*)(Cp + 12);
        float coef = dv.x * xv;
        float dec  = dv.y;
        s0.x = s0.x*dec + coef*B0.x; s0.y = s0.y*dec + coef*B0.y;
        s0.z = s0.z*dec + coef*B0.z; s0.w = s0.w*dec + coef*B0.w;
        s1.x = s1.x*dec + coef*B1.x; s1.y = s1.y*dec + coef*B1.y;
        s1.z = s1.z*dec + coef*B1.z; s1.w = s1.w*dec + coef*B1.w;
        s2.x = s2.x*dec + coef*B2.x; s2.y = s2.y*dec + coef*B2.y;
        s2.z = s2.z*dec + coef*B2.z; s2.w = s2.w*dec + coef*B2.w;
        s3.x = s3.x*dec + coef*B3.x; s3.y = s3.y*dec + coef*B3.y;
        s3.z = s3.z*dec + coef*B3.z; s3.w = s3.w*dec + coef*B3.w;
        float part = s0.x*C0.x + s0.y*C0.y + s0.z*C0.z + s0.w*C0.w
                   + s1.x*C1.x + s1.y*C1.y + s1.z*C1.z + s1.w*C1.w
                   + s2.x*C2.x + s2.y*C2.y + s2.z*C2.z + s2.w*C2.w
                   + s3.x*C3.x + s3.y*C3.y + s3.z*C3.z + s3.w*C3.w;
        part += __shfl_xor(part, 1);
        if ((lane & 1) == 0)
            yp[(size_t)i * D_INNER] = part + Dh * xv;
    }
}

// ---------------------------------------------------------------------------
// Kernel 5: gate*silu(z) + RMSNorm, accumulate G[b][i] = sum_l gn[b,l,i].
__global__ __launch_bounds__(256) void gate_acc_kernel(
        const float* __restrict__ yraw, const float* __restrict__ zx,
        const float* __restrict__ norm_w, float* __restrict__ G) {
    int b = blockIdx.x >> 5;
    int c = blockIdx.x & 31;
    int wave = threadIdx.x >> 6;
    int lane = threadIdx.x & 63;
    float acc0 = 0.f, acc1 = 0.f;
    int l0 = c * 64;
    for (int li = wave; li < 64; li += 4) {
        size_t bl = (size_t)b * SEQ + l0 + li;
        float2 yv = *(const float2*)(yraw + bl * D_INNER + lane * 2);
        float2 zv = *(const float2*)(zx + bl * D_IN_PROJ + lane * 2);
        float g0 = yv.x * (zv.x / (1.f + expf(-zv.x)));
        float g1 = yv.y * (zv.y / (1.f + expf(-zv.y)));
        float sq = g0 * g0 + g1 * g1;
#pragma unroll
        for (int m = 1; m < 64; m <<= 1) sq += __shfl_xor(sq, m);
        float rms = 1.0f / sqrtf(sq * (1.f / 128.f) + 1e-5f);
        acc0 += g0 * rms;
        acc1 += g1 * rms;
    }
    __shared__ float red[4][D_INNER];
    red[wave][lane * 2]     = acc0;
    red[wave][lane * 2 + 1] = acc1;
    __syncthreads();
    int tid = threadIdx.x;
    if (tid < D_INNER) {
        float s = red[0][tid] + red[1][tid] + red[2][tid] + red[3][tid];
        atomicAdd(&G[b * D_INNER + tid], s * norm_w[tid]);
    }
}

// ---------------------------------------------------------------------------
// Kernel 6: out[b][o] = b_cls[o] + (G[b] @ W_oc)[o] / SEQ
__global__ void head_kernel(const float* __restrict__ G,
                            const float* __restrict__ Woc,
                            const float* __restrict__ b_cls,
                            float* __restrict__ out) {
    int tid = threadIdx.x;
    if (tid >= BATCH * OUT_DIM) return;
    int b = tid / OUT_DIM, o = tid - b * OUT_DIM;
    float acc = 0.f;
#pragma unroll 8
    for (int i = 0; i < D_INNER; ++i)
        acc += G[b * D_INNER + i] * Woc[i * OUT_DIM + o];
    out[b * OUT_DIM + o] = acc * (1.f / (float)SEQ) + b_cls[o];
}

// ---------------------------------------------------------------------------
extern "C" void kernel_launch(void* const* d_in, const int* in_sizes, int n_in,
                              void* d_out, int out_size, void* d_ws, size_t ws_size,
                              hipStream_t stream) {
    const float* x       = (const float*)d_in[0];
    const float* W_lin   = (const float*)d_in[1];
    const float* b_lin   = (const float*)d_in[2];
    const float* W_in    = (const float*)d_in[3];
    const float* conv_w  = (const float*)d_in[4];
    const float* conv_b  = (const float*)d_in[5];
    const float* dt_bias = (const float*)d_in[6];
    const float* A_log   = (const float*)d_in[7];
    const float* Dp      = (const float*)d_in[8];
    const float* norm_w  = (const float*)d_in[9];
    const float* W_out   = (const float*)d_in[10];
    const float* W_cls   = (const float*)d_in[11];
    const float* b_cls   = (const float*)d_in[12];
    float* out = (float*)d_out;

    float* ws = (float*)d_ws;
    float* Wf   = ws + OFF_WF;
    float* bf   = ws + OFF_BF;
    float* zx   = ws + OFF_ZX;
    float* xBC  = ws + OFF_XBC;
    float* ddc  = ws + OFF_DD;
    float* yraw = ws + OFF_Y;
    float* G    = ws + OFF_G;
    float* Woc  = ws + OFF_WOC;
    float* sbuf = ws + OFF_SB;
    float* Pbuf = ws + OFF_P;

    // zero the G accumulator (ws is poisoned before every call)
    hipMemsetAsync(G, 0, BATCH * D_INNER * sizeof(float), stream);

    // 1) fused weight precompute
    fuse_w_kernel<<<(58 * D_IN_PROJ + D_INNER * OUT_DIM + 255) / 256, 256, 0, stream>>>(
        W_lin, b_lin, W_in, W_out, W_cls, Wf, bf, Woc);

    // 2) in-projection (LDS-staged, 24 rows/block)
    inproj_kernel<<<(BL + RTILE - 1) / RTILE, 256, 0, stream>>>(x, Wf, bf, zx);

    // 3) conv + dt/decay
    conv_dt_kernel<<<BATCH * (SEQ / CCH), 256, 0, stream>>>(zx, conv_w, conv_b, dt_bias, A_log, xBC, ddc);

    // 4) chunked selective scan (wave-per-head layout)
    scan_phase1_kernel<<<BATCH * NCHUNK, 256, 0, stream>>>(xBC, ddc, sbuf, Pbuf);
    scan_phase2_kernel<<<64 * 4, 256, 0, stream>>>(sbuf, Pbuf);
    scan_phase3_kernel<<<BATCH * NCHUNK, 256, 0, stream>>>(xBC, ddc, Dp, sbuf, yraw);

    // 5) gate + RMSNorm + channel accumulation
    gate_acc_kernel<<<BATCH * 32, 256, 0, stream>>>(yraw, zx, norm_w, G);

    // 6) classifier head
    head_kernel<<<1, 128, 0, stream>>>(G, Woc, b_cls, out);
}

// Round 8
// 213.944 us; speedup vs baseline: 1.0302x; 1.0302x over previous
//
#include <hip/hip_runtime.h>
#include <hip/hip_bf16.h>
#include <cmath>

// Problem constants
#define BATCH   16
#define SEQ     2048
#define IN_DIM  57
#define D_MODEL 64
#define HEADDIM 32
#define D_STATE 32
#define OUT_DIM 6
#define D_INNER 128
#define NHEADS  4
#define D_CONV  4
#define D_XBC   192          // D_INNER + 2*D_STATE
#define D_IN_PROJ 324        // 2*D_INNER + 2*D_STATE + NHEADS
#define BL      (BATCH*SEQ)  // 32768

// Chunked scan config
#define NCHUNK  64
#define CLEN    (SEQ / NCHUNK)   // 32

// inproj tiling
#define RTILE   24
#define XPAD    60

// conv_dt chunking
#define CCH     16

// Workspace layout (floats)
#define OFF_WF   ((size_t)0)
#define OFF_BF   ((size_t)18496)
#define OFF_ZX   ((size_t)18848)
#define OFF_XBC  (OFF_ZX  + (size_t)BL*D_IN_PROJ)
#define OFF_DD   (OFF_XBC + (size_t)BL*D_XBC)      // BL*8 interleaved {dt,dec}x4
#define OFF_G    (OFF_DD  + (size_t)BL*8)          // 2048
#define OFF_WOC  (OFF_G   + (size_t)2048)          // 896
#define OFF_SB   (OFF_WOC + (size_t)896)           // 64*NCHUNK*1024 chunk states
#define OFF_P    (OFF_SB  + (size_t)64*NCHUNK*1024)
// total ~ 21.4M floats ~ 86 MB

// ---------------------------------------------------------------------------
// Kernel 1: Wf = W_lin@W_in ; bf = b_lin@W_in ; W_oc = W_out@W_cls
__global__ void fuse_w_kernel(const float* __restrict__ W_lin,
                              const float* __restrict__ b_lin,
                              const float* __restrict__ W_in,
                              const float* __restrict__ W_out,
                              const float* __restrict__ W_cls,
                              float* __restrict__ Wf, float* __restrict__ bf,
                              float* __restrict__ Woc) {
    int idx = blockIdx.x * 256 + threadIdx.x;
    if (idx < 58 * D_IN_PROJ) {
        int r = idx / D_IN_PROJ;
        int j = idx - r * D_IN_PROJ;
        const float* v = (r < IN_DIM) ? (W_lin + r * D_MODEL) : b_lin;
        float acc = 0.f;
#pragma unroll 8
        for (int m = 0; m < D_MODEL; ++m) acc += v[m] * W_in[m * D_IN_PROJ + j];
        if (r < IN_DIM) Wf[r * D_IN_PROJ + j] = acc;
        else            bf[j] = acc;
    } else if (idx < 58 * D_IN_PROJ + D_INNER * OUT_DIM) {
        int idx2 = idx - 58 * D_IN_PROJ;
        int i = idx2 / OUT_DIM;
        int o = idx2 - i * OUT_DIM;
        float acc = 0.f;
#pragma unroll 8
        for (int j = 0; j < D_MODEL; ++j)
            acc += W_out[i * D_MODEL + j] * W_cls[j * OUT_DIM + o];
        Woc[i * OUT_DIM + o] = acc;
    }
}

// ---------------------------------------------------------------------------
// Kernel 2: LDS-staged in-projection. Block: 24 rows x 324 cols.
__global__ __launch_bounds__(256) void inproj_kernel(
        const float* __restrict__ x,
        const float* __restrict__ Wf,
        const float* __restrict__ bf,
        float* __restrict__ zx) {
    __shared__ float xs[RTILE][XPAD];
    int r0 = blockIdx.x * RTILE;
    for (int i = threadIdx.x; i < RTILE * IN_DIM; i += 256) {
        size_t g = (size_t)r0 * IN_DIM + i;
        float v = (g < (size_t)BL * IN_DIM) ? x[g] : 0.f;
        xs[i / IN_DIM][i % IN_DIM] = v;
    }
    __syncthreads();
    if (threadIdx.x >= 243) return;
    int rset = threadIdx.x / 81;
    int cg   = threadIdx.x - rset * 81;
    int j0   = cg * 4;
    float4 bias = *(const float4*)(bf + j0);
    float4 acc[8];
#pragma unroll
    for (int r = 0; r < 8; ++r) acc[r] = bias;
    const float* w = Wf + j0;
    const float* xrow = &xs[rset * 8][0];
#pragma unroll 2
    for (int kc = 0; kc < 14; ++kc) {
        int k = kc * 4;
        float4 wv0 = *(const float4*)(w + (size_t)(k + 0) * D_IN_PROJ);
        float4 wv1 = *(const float4*)(w + (size_t)(k + 1) * D_IN_PROJ);
        float4 wv2 = *(const float4*)(w + (size_t)(k + 2) * D_IN_PROJ);
        float4 wv3 = *(const float4*)(w + (size_t)(k + 3) * D_IN_PROJ);
#pragma unroll
        for (int r = 0; r < 8; ++r) {
            float4 xv = *(const float4*)(xrow + r * XPAD + k);
            acc[r].x += xv.x * wv0.x + xv.y * wv1.x + xv.z * wv2.x + xv.w * wv3.x;
            acc[r].y += xv.x * wv0.y + xv.y * wv1.y + xv.z * wv2.y + xv.w * wv3.y;
            acc[r].z += xv.x * wv0.z + xv.y * wv1.z + xv.z * wv2.z + xv.w * wv3.z;
            acc[r].w += xv.x * wv0.w + xv.y * wv1.w + xv.z * wv2.w + xv.w * wv3.w;
        }
    }
    {
        float4 wv = *(const float4*)(w + (size_t)56 * D_IN_PROJ);
#pragma unroll
        for (int r = 0; r < 8; ++r) {
            float xv = xrow[r * XPAD + 56];
            acc[r].x += xv * wv.x; acc[r].y += xv * wv.y;
            acc[r].z += xv * wv.z; acc[r].w += xv * wv.w;
        }
    }
#pragma unroll
    for (int r = 0; r < 8; ++r) {
        int row = r0 + rset * 8 + r;
        if (row < BL)
            *(float4*)(zx + (size_t)row * D_IN_PROJ + j0) = acc[r];
    }
}

// ---------------------------------------------------------------------------
// Kernel 3: depthwise causal conv(4) + bias + SiLU; dt softplus; decay exp(dt*A).
// Writes interleaved ddc[bl][8] = {dt0,dec0, dt1,dec1, dt2,dec2, dt3,dec3}.
__global__ __launch_bounds__(256) void conv_dt_kernel(
        const float* __restrict__ zx,
        const float* __restrict__ conv_w,
        const float* __restrict__ conv_b,
        const float* __restrict__ dt_bias,
        const float* __restrict__ A_log,
        float* __restrict__ xBC,
        float* __restrict__ ddc) {
    int b = blockIdx.x >> 7;          // SEQ/CCH = 128 chunks
    int c = blockIdx.x & 127;
    int l0 = c * CCH;
    int tid = threadIdx.x;
    size_t bl0 = (size_t)b * SEQ + l0;
    if (tid < D_XBC) {
        float w0 = conv_w[tid*4+0], w1 = conv_w[tid*4+1];
        float w2 = conv_w[tid*4+2], w3 = conv_w[tid*4+3];
        float cb = conv_b[tid];
        const float* src = zx + bl0 * D_IN_PROJ + D_INNER + tid;
        float vm1 = 0.f, vm2 = 0.f, vm3 = 0.f;
        if (c > 0) {
            vm1 = src[-(int)D_IN_PROJ];
            vm2 = src[-2*(int)D_IN_PROJ];
            vm3 = src[-3*(int)D_IN_PROJ];
        }
        float* dst = xBC + bl0 * D_XBC + tid;
#pragma unroll
        for (int i = 0; i < CCH; ++i) {
            float v0 = src[(size_t)i * D_IN_PROJ];
            float a = cb + v0 * w3 + vm1 * w2 + vm2 * w1 + vm3 * w0;
            dst[(size_t)i * D_XBC] = a / (1.f + expf(-a));   // SiLU
            vm3 = vm2; vm2 = vm1; vm1 = v0;
        }
    } else if (tid < D_XBC + NHEADS) {
        int h = tid - D_XBC;
        float bias = dt_bias[h];
        float A = -expf(A_log[h]);
        const float* src = zx + bl0 * D_IN_PROJ + 320 + h;
        float* dd = ddc + bl0 * 8 + h * 2;
#pragma unroll
        for (int i = 0; i < CCH; ++i) {
            float v = src[(size_t)i * D_IN_PROJ] + bias;
            float dtv = (v > 20.f) ? v : log1pf(expf(v));
            dd[(size_t)i * 8]     = dtv;
            dd[(size_t)i * 8 + 1] = expf(dtv * A);
        }
    }
}

// ---------------------------------------------------------------------------
// Chunked scan, phase 1. Block = (b, chunk); wave = head; lane -> (p = lane>>1,
// n-half = (lane&1)*16). 16 state floats per lane.
__global__ __launch_bounds__(256) void scan_phase1_kernel(
        const float* __restrict__ xBC, const float* __restrict__ ddc,
        float* __restrict__ sbuf, float* __restrict__ Pbuf) {
    int b = blockIdx.x >> 6;          // NCHUNK=64
    int c = blockIdx.x & 63;
    int h = threadIdx.x >> 6;
    int lane = threadIdx.x & 63;
    int p = lane >> 1;
    int n0 = (lane & 1) * 16;
    float4 s0 = make_float4(0.f,0.f,0.f,0.f), s1 = s0, s2 = s0, s3 = s0;
    float pacc = 1.f;
    size_t rbase = (size_t)b * SEQ + (size_t)c * CLEN;
    const float* xrow = xBC + rbase * D_XBC;
    const float* dd = ddc + rbase * 8 + h * 2;
#pragma unroll 4
    for (int i = 0; i < CLEN; ++i) {
        const float* row = xrow + (size_t)i * D_XBC;
        float2 dv = *(const float2*)(dd + (size_t)i * 8);
        float xv = row[h * HEADDIM + p];
        const float* Bp = row + D_INNER + n0;
        float4 B0 = *(const float4*)(Bp + 0);
        float4 B1 = *(const float4*)(Bp + 4);
        float4 B2 = *(const float4*)(Bp + 8);
        float4 B3 = *(const float4*)(Bp + 12);
        float coef = dv.x * xv;
        float dec  = dv.y;
        s0.x = s0.x*dec + coef*B0.x; s0.y = s0.y*dec + coef*B0.y;
        s0.z = s0.z*dec + coef*B0.z; s0.w = s0.w*dec + coef*B0.w;
        s1.x = s1.x*dec + coef*B1.x; s1.y = s1.y*dec + coef*B1.y;
        s1.z = s1.z*dec + coef*B1.z; s1.w = s1.w*dec + coef*B1.w;
        s2.x = s2.x*dec + coef*B2.x; s2.y = s2.y*dec + coef*B2.y;
        s2.z = s2.z*dec + coef*B2.z; s2.w = s2.w*dec + coef*B2.w;
        s3.x = s3.x*dec + coef*B3.x; s3.y = s3.y*dec + coef*B3.y;
        s3.z = s3.z*dec + coef*B3.z; s3.w = s3.w*dec + coef*B3.w;
        pacc *= dec;
    }
    int bh = b * NHEADS + h;
    float4* sp = (float4*)sbuf + ((size_t)bh * NCHUNK + c) * 256;
    sp[0*64 + lane] = s0;
    sp[1*64 + lane] = s1;
    sp[2*64 + lane] = s2;
    sp[3*64 + lane] = s3;
    if (lane == 0) Pbuf[bh * NCHUNK + c] = pacc;
}

// ---------------------------------------------------------------------------
// Phase 2: combine chunk states. Grid 256 blocks; thread = one float slot,
// coalesced. sbuf[c] <- initial state for chunk c.
__global__ __launch_bounds__(256) void scan_phase2_kernel(
        float* __restrict__ sbuf, const float* __restrict__ Pbuf) {
    int bh = blockIdx.x >> 2;
    int q  = blockIdx.x & 3;
    int idx = q * 256 + threadIdx.x;     // 0..1023
    float run = 0.f;
    for (int c = 0; c < NCHUNK; ++c) {
        size_t a = ((size_t)bh * NCHUNK + c) * 1024 + idx;
        float tmp = sbuf[a];
        float Pv = Pbuf[bh * NCHUNK + c];
        sbuf[a] = run;
        run = run * Pv + tmp;
    }
}

// ---------------------------------------------------------------------------
// Phase 3 (fused): seeded re-run producing y in LDS, then gate*silu(z) +
// RMSNorm + accumulate G. No yraw global round-trip.
__global__ __launch_bounds__(256) void scan_phase3_kernel(
        const float* __restrict__ xBC, const float* __restrict__ ddc,
        const float* __restrict__ zx, const float* __restrict__ Dp,
        const float* __restrict__ sbuf, const float* __restrict__ norm_w,
        float* __restrict__ G) {
    int b = blockIdx.x >> 6;          // NCHUNK=64
    int c = blockIdx.x & 63;
    int h = threadIdx.x >> 6;
    int lane = threadIdx.x & 63;
    int p = lane >> 1;
    int n0 = (lane & 1) * 16;
    int bh = b * NHEADS + h;
    const float4* sp = (const float4*)sbuf + ((size_t)bh * NCHUNK + c) * 256;
    float4 s0 = sp[0*64 + lane];
    float4 s1 = sp[1*64 + lane];
    float4 s2 = sp[2*64 + lane];
    float4 s3 = sp[3*64 + lane];
    float Dh = Dp[h];
    size_t rbase = (size_t)b * SEQ + (size_t)c * CLEN;
    const float* xrow = xBC + rbase * D_XBC;
    const float* dd = ddc + rbase * 8 + h * 2;
    __shared__ float ylds[CLEN][D_INNER];   // 32*128*4 = 16 KB
    __shared__ float red[4][D_INNER];
#pragma unroll 4
    for (int i = 0; i < CLEN; ++i) {
        const float* row = xrow + (size_t)i * D_XBC;
        float2 dv = *(const float2*)(dd + (size_t)i * 8);
        float xv = row[h * HEADDIM + p];
        const float* Bp = row + D_INNER + n0;
        const float* Cp = row + D_INNER + D_STATE + n0;
        float4 B0 = *(const float4*)(Bp + 0);
        float4 B1 = *(const float4*)(Bp + 4);
        float4 B2 = *(const float4*)(Bp + 8);
        float4 B3 = *(const float4*)(Bp + 12);
        float4 C0 = *(const float4*)(Cp + 0);
        float4 C1 = *(const float4*)(Cp + 4);
        float4 C2 = *(const float4*)(Cp + 8);
        float4 C3 = *(const float4*)(Cp + 12);
        float coef = dv.x * xv;
        float dec  = dv.y;
        s0.x = s0.x*dec + coef*B0.x; s0.y = s0.y*dec + coef*B0.y;
        s0.z = s0.z*dec + coef*B0.z; s0.w = s0.w*dec + coef*B0.w;
        s1.x = s1.x*dec + coef*B1.x; s1.y = s1.y*dec + coef*B1.y;
        s1.z = s1.z*dec + coef*B1.z; s1.w = s1.w*dec + coef*B1.w;
        s2.x = s2.x*dec + coef*B2.x; s2.y = s2.y*dec + coef*B2.y;
        s2.z = s2.z*dec + coef*B2.z; s2.w = s2.w*dec + coef*B2.w;
        s3.x = s3.x*dec + coef*B3.x; s3.y = s3.y*dec + coef*B3.y;
        s3.z = s3.z*dec + coef*B3.z; s3.w = s3.w*dec + coef*B3.w;
        float part = s0.x*C0.x + s0.y*C0.y + s0.z*C0.z + s0.w*C0.w
                   + s1.x*C1.x + s1.y*C1.y + s1.z*C1.z + s1.w*C1.w
                   + s2.x*C2.x + s2.y*C2.y + s2.z*C2.z + s2.w*C2.w
                   + s3.x*C3.x + s3.y*C3.y + s3.z*C3.z + s3.w*C3.w;
        part += __shfl_xor(part, 1);
        if ((lane & 1) == 0)
            ylds[i][h * HEADDIM + p] = part + Dh * xv;
    }
    __syncthreads();
    // gate + RMSNorm from LDS; wave h handles rows h, h+4, ...
    float acc0 = 0.f, acc1 = 0.f;
    for (int r = h; r < CLEN; r += 4) {
        size_t bl = rbase + r;
        float2 yv = *(const float2*)(&ylds[r][lane * 2]);
        float2 zv = *(const float2*)(zx + bl * D_IN_PROJ + lane * 2);
        float g0 = yv.x * (zv.x / (1.f + expf(-zv.x)));
        float g1 = yv.y * (zv.y / (1.f + expf(-zv.y)));
        float sq = g0 * g0 + g1 * g1;
#pragma unroll
        for (int m = 1; m < 64; m <<= 1) sq += __shfl_xor(sq, m);
        float rms = 1.0f / sqrtf(sq * (1.f / 128.f) + 1e-5f);
        acc0 += g0 * rms;
        acc1 += g1 * rms;
    }
    red[h][lane * 2]     = acc0;
    red[h][lane * 2 + 1] = acc1;
    __syncthreads();
    int tid = threadIdx.x;
    if (tid < D_INNER) {
        float s = red[0][tid] + red[1][tid] + red[2][tid] + red[3][tid];
        atomicAdd(&G[b * D_INNER + tid], s * norm_w[tid]);
    }
}

// ---------------------------------------------------------------------------
// Kernel 6: out[b][o] = b_cls[o] + (G[b] @ W_oc)[o] / SEQ
__global__ void head_kernel(const float* __restrict__ G,
                            const float* __restrict__ Woc,
                            const float* __restrict__ b_cls,
                            float* __restrict__ out) {
    int tid = threadIdx.x;
    if (tid >= BATCH * OUT_DIM) return;
    int b = tid / OUT_DIM, o = tid - b * OUT_DIM;
    float acc = 0.f;
#pragma unroll 8
    for (int i = 0; i < D_INNER; ++i)
        acc += G[b * D_INNER + i] * Woc[i * OUT_DIM + o];
    out[b * OUT_DIM + o] = acc * (1.f / (float)SEQ) + b_cls[o];
}

// ---------------------------------------------------------------------------
extern "C" void kernel_launch(void* const* d_in, const int* in_sizes, int n_in,
                              void* d_out, int out_size, void* d_ws, size_t ws_size,
                              hipStream_t stream) {
    const float* x       = (const float*)d_in[0];
    const float* W_lin   = (const float*)d_in[1];
    const float* b_lin   = (const float*)d_in[2];
    const float* W_in    = (const float*)d_in[3];
    const float* conv_w  = (const float*)d_in[4];
    const float* conv_b  = (const float*)d_in[5];
    const float* dt_bias = (const float*)d_in[6];
    const float* A_log   = (const float*)d_in[7];
    const float* Dp      = (const float*)d_in[8];
    const float* norm_w  = (const float*)d_in[9];
    const float* W_out   = (const float*)d_in[10];
    const float* W_cls   = (const float*)d_in[11];
    const float* b_cls   = (const float*)d_in[12];
    float* out = (float*)d_out;

    float* ws = (float*)d_ws;
    float* Wf   = ws + OFF_WF;
    float* bf   = ws + OFF_BF;
    float* zx   = ws + OFF_ZX;
    float* xBC  = ws + OFF_XBC;
    float* ddc  = ws + OFF_DD;
    float* G    = ws + OFF_G;
    float* Woc  = ws + OFF_WOC;
    float* sbuf = ws + OFF_SB;
    float* Pbuf = ws + OFF_P;

    // zero the G accumulator (ws is poisoned before every call)
    hipMemsetAsync(G, 0, BATCH * D_INNER * sizeof(float), stream);

    // 1) fused weight precompute
    fuse_w_kernel<<<(58 * D_IN_PROJ + D_INNER * OUT_DIM + 255) / 256, 256, 0, stream>>>(
        W_lin, b_lin, W_in, W_out, W_cls, Wf, bf, Woc);

    // 2) in-projection (LDS-staged, 24 rows/block)
    inproj_kernel<<<(BL + RTILE - 1) / RTILE, 256, 0, stream>>>(x, Wf, bf, zx);

    // 3) conv + dt/decay
    conv_dt_kernel<<<BATCH * (SEQ / CCH), 256, 0, stream>>>(zx, conv_w, conv_b, dt_bias, A_log, xBC, ddc);

    // 4) chunked selective scan (wave-per-head, 1024 blocks)
    scan_phase1_kernel<<<BATCH * NCHUNK, 256, 0, stream>>>(xBC, ddc, sbuf, Pbuf);
    scan_phase2_kernel<<<64 * 4, 256, 0, stream>>>(sbuf, Pbuf);
    // phase 3 fused with gate+RMSNorm+G accumulation
    scan_phase3_kernel<<<BATCH * NCHUNK, 256, 0, stream>>>(xBC, ddc, zx, Dp, sbuf, norm_w, G);

    // 5) classifier head
    head_kernel<<<1, 128, 0, stream>>>(G, Woc, b_cls, out);
}